// Round 5
// baseline (119.943 us; speedup 1.0000x reference)
//
#include <hip/hip_runtime.h>
#include <hip/hip_bf16.h>

#define NB   4
#define NC   256
#define NPOS 4096
#define NDQK 32

typedef __bf16 bf16x8  __attribute__((ext_vector_type(8)));
typedef float  f32x16  __attribute__((ext_vector_type(16)));

typedef __attribute__((address_space(3))) char*       lds_ptr_t;
typedef const __attribute__((address_space(1))) char* glb_ptr_t;

// =====================================================================
// Projection kernel: Y[o][n] = sum_c W[o][c] * x[c][n] + b[o], bf16 MFMA.
// ot 0..7 -> Wv rows ot*32 (out V[b][c][n]), ot==8 -> Wq (pre-scaled by
// log2e, out Q[b][n][d]), ot==9 -> Wk.
// =====================================================================
__global__ __launch_bounds__(256) void proj_kernel(
    const float* __restrict__ x,
    const float* __restrict__ Wq, const float* __restrict__ bq,
    const float* __restrict__ Wk, const float* __restrict__ bk,
    const float* __restrict__ Wv, const float* __restrict__ bv,
    __hip_bfloat16* __restrict__ Qb, __hip_bfloat16* __restrict__ Kb,
    __hip_bfloat16* __restrict__ Vb)
{
    const int t   = threadIdx.x;
    const int l   = t & 63;
    const int w   = t >> 6;
    const int hi  = l >> 5;
    const int col = l & 31;
    const int row = l & 31;

    const int item = blockIdx.x * 4 + w;     // 0..1279
    const int nch  = item & 31;              // 32 n-chunks of 128
    const int rest = item >> 5;              // 0..39
    const int ot   = rest % 10;
    const int b    = rest / 10;

    const float* W;  const float* bs;  int o0;
    if (ot < 8)       { W = Wv; bs = bv; o0 = ot * 32; }
    else if (ot == 8) { W = Wq; bs = bq; o0 = 0; }
    else              { W = Wk; bs = bk; o0 = 0; }
    const float qscale = (ot == 8) ? 1.44269504088896f : 1.0f;

    bf16x8 wf[16];
    const float* Wr = W + (size_t)(o0 + row) * NC + 8 * hi;
    #pragma unroll
    for (int kk = 0; kk < 16; ++kk) {
        const float4 a = *reinterpret_cast<const float4*>(Wr + kk * 16);
        const float4 c = *reinterpret_cast<const float4*>(Wr + kk * 16 + 4);
        bf16x8 f;
        f[0] = (__bf16)a.x; f[1] = (__bf16)a.y; f[2] = (__bf16)a.z; f[3] = (__bf16)a.w;
        f[4] = (__bf16)c.x; f[5] = (__bf16)c.y; f[6] = (__bf16)c.z; f[7] = (__bf16)c.w;
        wf[kk] = f;
    }
    float brow[16];
    #pragma unroll
    for (int r = 0; r < 16; ++r)
        brow[r] = bs[o0 + (r & 3) + 8 * (r >> 2) + 4 * hi];

    #pragma unroll 1
    for (int tile = 0; tile < 4; ++tile) {
        const int n0 = nch * 128 + tile * 32;
        f32x16 acc;
        #pragma unroll
        for (int r = 0; r < 16; ++r) acc[r] = 0.f;

        const float* xcol = x + (size_t)b * NC * NPOS + n0 + col;
        #pragma unroll
        for (int kk = 0; kk < 16; ++kk) {
            bf16x8 bf;
            #pragma unroll
            for (int i = 0; i < 8; ++i)
                bf[i] = (__bf16)xcol[(size_t)(kk * 16 + 8 * hi + i) * NPOS];
            acc = __builtin_amdgcn_mfma_f32_32x32x16_bf16(wf[kk], bf, acc, 0, 0, 0);
        }

        if (ot < 8) {
            #pragma unroll
            for (int r = 0; r < 16; ++r) {
                const int orow = (r & 3) + 8 * (r >> 2) + 4 * hi;
                Vb[((size_t)(b * NC + o0 + orow)) * NPOS + n0 + col] =
                    __float2bfloat16(acc[r] + brow[r]);
            }
        } else {
            __hip_bfloat16* dst = (ot == 8) ? Qb : Kb;
            #pragma unroll
            for (int r = 0; r < 16; ++r) {
                const int orow = (r & 3) + 8 * (r >> 2) + 4 * hi;
                dst[((size_t)(b * NPOS) + n0 + col) * NDQK + orow] =
                    __float2bfloat16((acc[r] + brow[r]) * qscale);
            }
        }
    }
}

// =====================================================================
// Fused flash attention + residual, 32x32x16 MFMA, linear softmax
// (exp2 with log2e folded into Q; no online max needed at |S|<~50).
//
// Wave = 32 q x 64 ch, block = 4 waves (c-split), fully wave-private.
// V staged global->LDS (global_load_lds w=16), double-buffered.
// LDS sigma: chunk g of row r stored at slot (g + (r>>1)) & 3 -> each
// 8-lane phase of ds_read_b128 covers all 8 bank-quads exactly once
// (conflict-free; the r4 rotation only hit 8 aliased quads).
// K prefetched into registers one j-tile ahead (hides L2 latency).
// Counted s_waitcnt vmcnt(4): >=4 newer VMEM ops always precede the
// wait, so the previous tile's STAGE is forced retired regardless of
// where the compiler places the K loads. No __syncthreads anywhere.
// =====================================================================
__global__ __launch_bounds__(256, 4) void attn_kernel(
    const __hip_bfloat16* __restrict__ Qb,
    const __hip_bfloat16* __restrict__ Kb,
    const __hip_bfloat16* __restrict__ Vb,
    const float* __restrict__ x,
    const float* __restrict__ gamma,
    float* __restrict__ out)
{
    __shared__ __align__(16) char smem[32768];   // 4 waves x 2 bufs x 4KB
    const int t   = threadIdx.x;
    const int l   = t & 63;
    const int w   = t >> 6;
    const int hi  = l >> 5;
    const int q   = l & 31;
    const int bx  = blockIdx.x;
    const int b   = (bx >> 1) & 3;               // XCD-pair -> one batch
    const int qb  = ((bx >> 3) << 1) | (bx & 1); // 0..127
    const int q0  = qb * 32;
    const int c0w = w * 64;

    const __bf16* Qp = reinterpret_cast<const __bf16*>(Qb) + (size_t)b * NPOS * NDQK;
    const __bf16* Kp = reinterpret_cast<const __bf16*>(Kb) + (size_t)b * NPOS * NDQK;
    const __bf16* Vp = reinterpret_cast<const __bf16*>(Vb) + (size_t)b * NC * NPOS;

    // swap bits 2<->3 of the A-row index so S lands exactly in PV B-frag order
    const int perm = (q & 0x13) | ((q & 4) << 1) | ((q & 8) >> 1);

    const bf16x8 qf0 = *reinterpret_cast<const bf16x8*>(Qp + (size_t)(q0 + q) * NDQK + 8 * hi);
    const bf16x8 qf1 = *reinterpret_cast<const bf16x8*>(Qp + (size_t)(q0 + q) * NDQK + 16 + 8 * hi);

    const __bf16* Kbase = Kp + (size_t)perm * NDQK + 8 * hi;

    // ---- V staging: wave-private LDS tile [64 c][32 j], 64B rows.
    // Slot c of LDS row r holds global chunk g = (c - (r>>1)) & 3.
    __bf16* vb = reinterpret_cast<__bf16*>(smem) + w * 4096;  // [2][2048] elems
    const int  srow   = l >> 2;
    const int  schunk = ((l & 3) - (l >> 3)) & 3;
    const __bf16* vsrc = Vp + (size_t)(c0w + srow) * NPOS + schunk * 8;

    #define STAGE(buf, j0_) do {                                                   \
        __builtin_amdgcn_global_load_lds((glb_ptr_t)(const char*)(vsrc + (j0_)),              \
            (lds_ptr_t)(char*)(vb + (buf) * 2048),        16, 0, 0);               \
        __builtin_amdgcn_global_load_lds((glb_ptr_t)(const char*)(vsrc + 16 * NPOS + (j0_)),  \
            (lds_ptr_t)(char*)(vb + (buf) * 2048 + 512),  16, 0, 0);               \
        __builtin_amdgcn_global_load_lds((glb_ptr_t)(const char*)(vsrc + 32 * NPOS + (j0_)),  \
            (lds_ptr_t)(char*)(vb + (buf) * 2048 + 1024), 16, 0, 0);               \
        __builtin_amdgcn_global_load_lds((glb_ptr_t)(const char*)(vsrc + 48 * NPOS + (j0_)),  \
            (lds_ptr_t)(char*)(vb + (buf) * 2048 + 1536), 16, 0, 0);               \
    } while (0)

    // fragment read offsets: row cl0 (+32 via +1024 elems), swizzled slot
    const int cl0 = l & 31;
    const int rot = cl0 >> 1;
    const int ch0 = (hi + rot) & 3;          // j-chunk hi
    const int ch1 = (2 + hi + rot) & 3;      // j-chunk 2+hi
    const int ro  = cl0 * 32;

    f32x16 acc0, acc1;
    #pragma unroll
    for (int r = 0; r < 16; ++r) { acc0[r] = 0.f; acc1[r] = 0.f; }
    float lp = 0.f;

    STAGE(0, 0);   // prologue: V tile jt=0 -> buf 0
    // K prefetch: current tile's fragments in registers
    bf16x8 kc0 = *reinterpret_cast<const bf16x8*>(Kbase);
    bf16x8 kc1 = *reinterpret_cast<const bf16x8*>(Kbase + 16);

    #pragma unroll 1
    for (int jt = 0; jt < 128; ++jt) {
        const int j0  = jt * 32;
        const int cur = jt & 1;

        bf16x8 kn0 = kc0, kn1 = kc1;
        if (jt != 127) {
            STAGE(cur ^ 1, j0 + 32);
            kn0 = *reinterpret_cast<const bf16x8*>(Kbase + (size_t)(j0 + 32) * NDQK);
            kn1 = *reinterpret_cast<const bf16x8*>(Kbase + (size_t)(j0 + 32) * NDQK + 16);
            asm volatile("s_waitcnt vmcnt(4)" ::: "memory");
        } else {
            asm volatile("s_waitcnt vmcnt(0)" ::: "memory");
        }
        __builtin_amdgcn_sched_barrier(0);

        const __bf16* vcur = vb + cur * 2048;
        const bf16x8 vf00 = *reinterpret_cast<const bf16x8*>(vcur + ro + ch0 * 8);
        const bf16x8 vf01 = *reinterpret_cast<const bf16x8*>(vcur + ro + ch1 * 8);
        const bf16x8 vf10 = *reinterpret_cast<const bf16x8*>(vcur + 1024 + ro + ch0 * 8);
        const bf16x8 vf11 = *reinterpret_cast<const bf16x8*>(vcur + 1024 + ro + ch1 * 8);

        f32x16 s;
        #pragma unroll
        for (int r = 0; r < 16; ++r) s[r] = 0.f;
        s = __builtin_amdgcn_mfma_f32_32x32x16_bf16(kc0, qf0, s, 0, 0, 0);
        s = __builtin_amdgcn_mfma_f32_32x32x16_bf16(kc1, qf1, s, 0, 0, 0);

        float p[16];
        #pragma unroll
        for (int r = 0; r < 16; ++r) p[r] = __builtin_amdgcn_exp2f(s[r]);

        const float s0 = (p[0] + p[1]) + (p[2] + p[3]);
        const float s1 = (p[4] + p[5]) + (p[6] + p[7]);
        const float s2 = (p[8] + p[9]) + (p[10] + p[11]);
        const float s3 = (p[12] + p[13]) + (p[14] + p[15]);
        lp += (s0 + s1) + (s2 + s3);

        bf16x8 pa0, pa1;
        #pragma unroll
        for (int i = 0; i < 8; ++i) { pa0[i] = (__bf16)p[i]; pa1[i] = (__bf16)p[8 + i]; }

        acc0 = __builtin_amdgcn_mfma_f32_32x32x16_bf16(vf00, pa0, acc0, 0, 0, 0);
        acc0 = __builtin_amdgcn_mfma_f32_32x32x16_bf16(vf01, pa1, acc0, 0, 0, 0);
        acc1 = __builtin_amdgcn_mfma_f32_32x32x16_bf16(vf10, pa0, acc1, 0, 0, 0);
        acc1 = __builtin_amdgcn_mfma_f32_32x32x16_bf16(vf11, pa1, acc1, 0, 0, 0);

        kc0 = kn0;
        kc1 = kn1;
    }
    #undef STAGE

    // epilogue: l is lane-local per q after one shfl; direct fused store
    const float lt = lp + __shfl_xor(lp, 32);
    const float gl = gamma[0] / lt;

    #pragma unroll
    for (int r = 0; r < 16; ++r) {
        const int crow = (r & 3) + 8 * (r >> 2) + 4 * hi;
        const size_t g0 = ((size_t)(b * NC + c0w + crow)) * NPOS + q0 + q;
        const size_t g1 = g0 + (size_t)32 * NPOS;
        out[g0] = x[g0] + gl * acc0[r];
        out[g1] = x[g1] + gl * acc1[r];
    }
}

extern "C" void kernel_launch(void* const* d_in, const int* in_sizes, int n_in,
                              void* d_out, int out_size, void* d_ws, size_t ws_size,
                              hipStream_t stream) {
    (void)in_sizes; (void)n_in; (void)out_size; (void)ws_size;
    const float* x     = (const float*)d_in[0];
    const float* Wq    = (const float*)d_in[1];
    const float* bq    = (const float*)d_in[2];
    const float* Wk    = (const float*)d_in[3];
    const float* bk    = (const float*)d_in[4];
    const float* Wv    = (const float*)d_in[5];
    const float* bv    = (const float*)d_in[6];
    const float* gamma = (const float*)d_in[7];
    float* out = (float*)d_out;

    char* ws = (char*)d_ws;
    __hip_bfloat16* Qb = (__hip_bfloat16*)(ws);                    // 1 MB
    __hip_bfloat16* Kb = (__hip_bfloat16*)(ws + (1u << 20));       // 1 MB
    __hip_bfloat16* Vb = (__hip_bfloat16*)(ws + (2u << 20));       // 8 MB

    proj_kernel<<<320, 256, 0, stream>>>(x, Wq, bq, Wk, bk, Wv, bv, Qb, Kb, Vb);
    attn_kernel<<<512, 256, 0, stream>>>(Qb, Kb, Vb, x, gamma, out);
}

// Round 6
// 114.590 us; speedup vs baseline: 1.0467x; 1.0467x over previous
//
#include <hip/hip_runtime.h>
#include <hip/hip_bf16.h>

#define NB   4
#define NC   256
#define NPOS 4096
#define NDQK 32

typedef __bf16 bf16x8  __attribute__((ext_vector_type(8)));
typedef float  f32x16  __attribute__((ext_vector_type(16)));

typedef __attribute__((address_space(3))) char*       lds_ptr_t;
typedef const __attribute__((address_space(1))) char* glb_ptr_t;

// =====================================================================
// Projection kernel: Y[o][n] = sum_c W[o][c] * x[c][n] + b[o], bf16 MFMA.
// ot 0..7 -> Wv rows ot*32 (out V[b][c][n]), ot==8 -> Wq (pre-scaled by
// log2e, out Q[b][n][d]), ot==9 -> Wk.
// =====================================================================
__global__ __launch_bounds__(256) void proj_kernel(
    const float* __restrict__ x,
    const float* __restrict__ Wq, const float* __restrict__ bq,
    const float* __restrict__ Wk, const float* __restrict__ bk,
    const float* __restrict__ Wv, const float* __restrict__ bv,
    __hip_bfloat16* __restrict__ Qb, __hip_bfloat16* __restrict__ Kb,
    __hip_bfloat16* __restrict__ Vb)
{
    const int t   = threadIdx.x;
    const int l   = t & 63;
    const int w   = t >> 6;
    const int hi  = l >> 5;
    const int col = l & 31;
    const int row = l & 31;

    const int item = blockIdx.x * 4 + w;     // 0..1279
    const int nch  = item & 31;              // 32 n-chunks of 128
    const int rest = item >> 5;              // 0..39
    const int ot   = rest % 10;
    const int b    = rest / 10;

    const float* W;  const float* bs;  int o0;
    if (ot < 8)       { W = Wv; bs = bv; o0 = ot * 32; }
    else if (ot == 8) { W = Wq; bs = bq; o0 = 0; }
    else              { W = Wk; bs = bk; o0 = 0; }
    const float qscale = (ot == 8) ? 1.44269504088896f : 1.0f;

    bf16x8 wf[16];
    const float* Wr = W + (size_t)(o0 + row) * NC + 8 * hi;
    #pragma unroll
    for (int kk = 0; kk < 16; ++kk) {
        const float4 a = *reinterpret_cast<const float4*>(Wr + kk * 16);
        const float4 c = *reinterpret_cast<const float4*>(Wr + kk * 16 + 4);
        bf16x8 f;
        f[0] = (__bf16)a.x; f[1] = (__bf16)a.y; f[2] = (__bf16)a.z; f[3] = (__bf16)a.w;
        f[4] = (__bf16)c.x; f[5] = (__bf16)c.y; f[6] = (__bf16)c.z; f[7] = (__bf16)c.w;
        wf[kk] = f;
    }
    float brow[16];
    #pragma unroll
    for (int r = 0; r < 16; ++r)
        brow[r] = bs[o0 + (r & 3) + 8 * (r >> 2) + 4 * hi];

    #pragma unroll 1
    for (int tile = 0; tile < 4; ++tile) {
        const int n0 = nch * 128 + tile * 32;
        f32x16 acc;
        #pragma unroll
        for (int r = 0; r < 16; ++r) acc[r] = 0.f;

        const float* xcol = x + (size_t)b * NC * NPOS + n0 + col;
        #pragma unroll
        for (int kk = 0; kk < 16; ++kk) {
            bf16x8 bf;
            #pragma unroll
            for (int i = 0; i < 8; ++i)
                bf[i] = (__bf16)xcol[(size_t)(kk * 16 + 8 * hi + i) * NPOS];
            acc = __builtin_amdgcn_mfma_f32_32x32x16_bf16(wf[kk], bf, acc, 0, 0, 0);
        }

        if (ot < 8) {
            #pragma unroll
            for (int r = 0; r < 16; ++r) {
                const int orow = (r & 3) + 8 * (r >> 2) + 4 * hi;
                Vb[((size_t)(b * NC + o0 + orow)) * NPOS + n0 + col] =
                    __float2bfloat16(acc[r] + brow[r]);
            }
        } else {
            __hip_bfloat16* dst = (ot == 8) ? Qb : Kb;
            #pragma unroll
            for (int r = 0; r < 16; ++r) {
                const int orow = (r & 3) + 8 * (r >> 2) + 4 * hi;
                dst[((size_t)(b * NPOS) + n0 + col) * NDQK + orow] =
                    __float2bfloat16((acc[r] + brow[r]) * qscale);
            }
        }
    }
}

// =====================================================================
// Fused flash attention + residual, 32x32x16 MFMA, linear softmax
// (exp2 with log2e folded into Q; no online max needed at |S|<~50).
//
// Wave = 32 q x 64 ch, block = 4 waves (c-split), fully wave-private.
// V staged global->LDS (global_load_lds w=16), 4 buffers, staged TWO
// tiles ahead; counted s_waitcnt vmcnt(8) (FIFO: >=12 newer VMEM ops
// precede each wait, so the target tile's STAGE is always retired).
// sched_barrier(0x7F): only DS ops are pinned after the wait — VALU/
// MFMA/VMEM flow across iterations, letting #pragma unroll 2 pipeline
// tile T's PV/softmax with tile T+1's loads/QK^T. No __syncthreads.
// LDS sigma (slot c of row r holds chunk (c-(r>>1))&3) as round 5.
// =====================================================================
__global__ __launch_bounds__(256, 2) void attn_kernel(
    const __hip_bfloat16* __restrict__ Qb,
    const __hip_bfloat16* __restrict__ Kb,
    const __hip_bfloat16* __restrict__ Vb,
    const float* __restrict__ x,
    const float* __restrict__ gamma,
    float* __restrict__ out)
{
    __shared__ __align__(16) char smem[65536];   // 4 waves x 4 bufs x 4KB
    const int t   = threadIdx.x;
    const int l   = t & 63;
    const int w   = t >> 6;
    const int hi  = l >> 5;
    const int q   = l & 31;
    const int bx  = blockIdx.x;
    const int b   = (bx >> 1) & 3;               // XCD-pair -> one batch
    const int qb  = ((bx >> 3) << 1) | (bx & 1); // 0..127
    const int q0  = qb * 32;
    const int c0w = w * 64;

    const __bf16* Qp = reinterpret_cast<const __bf16*>(Qb) + (size_t)b * NPOS * NDQK;
    const __bf16* Kp = reinterpret_cast<const __bf16*>(Kb) + (size_t)b * NPOS * NDQK;
    const __bf16* Vp = reinterpret_cast<const __bf16*>(Vb) + (size_t)b * NC * NPOS;

    // swap bits 2<->3 of the A-row index so S lands exactly in PV B-frag order
    const int perm = (q & 0x13) | ((q & 4) << 1) | ((q & 8) >> 1);

    const bf16x8 qf0 = *reinterpret_cast<const bf16x8*>(Qp + (size_t)(q0 + q) * NDQK + 8 * hi);
    const bf16x8 qf1 = *reinterpret_cast<const bf16x8*>(Qp + (size_t)(q0 + q) * NDQK + 16 + 8 * hi);

    const __bf16* Kbase = Kp + (size_t)perm * NDQK + 8 * hi;

    // ---- V staging: wave-private LDS tile [64 c][32 j], 64B rows.
    // Slot c of LDS row r holds global chunk g = (c - (r>>1)) & 3.
    __bf16* vb = reinterpret_cast<__bf16*>(smem) + w * 8192;  // [4][2048] elems
    const int  srow   = l >> 2;
    const int  schunk = ((l & 3) - (l >> 3)) & 3;
    const __bf16* vsrc = Vp + (size_t)(c0w + srow) * NPOS + schunk * 8;

    #define STAGE(buf, j0_) do {                                                   \
        __builtin_amdgcn_global_load_lds((glb_ptr_t)(const char*)(vsrc + (j0_)),              \
            (lds_ptr_t)(char*)(vb + (buf) * 2048),        16, 0, 0);               \
        __builtin_amdgcn_global_load_lds((glb_ptr_t)(const char*)(vsrc + 16 * NPOS + (j0_)),  \
            (lds_ptr_t)(char*)(vb + (buf) * 2048 + 512),  16, 0, 0);               \
        __builtin_amdgcn_global_load_lds((glb_ptr_t)(const char*)(vsrc + 32 * NPOS + (j0_)),  \
            (lds_ptr_t)(char*)(vb + (buf) * 2048 + 1024), 16, 0, 0);               \
        __builtin_amdgcn_global_load_lds((glb_ptr_t)(const char*)(vsrc + 48 * NPOS + (j0_)),  \
            (lds_ptr_t)(char*)(vb + (buf) * 2048 + 1536), 16, 0, 0);               \
    } while (0)

    // fragment read offsets: row cl0 (+32 via +1024 elems), swizzled slot
    const int cl0 = l & 31;
    const int rot = cl0 >> 1;
    const int ch0 = (hi + rot) & 3;          // j-chunk hi
    const int ch1 = (2 + hi + rot) & 3;      // j-chunk 2+hi
    const int ro  = cl0 * 32;

    f32x16 acc0, acc1;
    #pragma unroll
    for (int r = 0; r < 16; ++r) { acc0[r] = 0.f; acc1[r] = 0.f; }
    float lp = 0.f;

    STAGE(0, 0);     // prologue: tiles 0,1 in flight
    STAGE(1, 32);

    #pragma unroll 2
    for (int jt = 0; jt < 128; ++jt) {
        const int j0 = jt * 32;

        if (jt < 126) {
            STAGE((jt + 2) & 3, j0 + 64);
            asm volatile("s_waitcnt vmcnt(8)" ::: "memory");
        } else if (jt == 126) {
            asm volatile("s_waitcnt vmcnt(4)" ::: "memory");
        } else {
            asm volatile("s_waitcnt vmcnt(0)" ::: "memory");
        }
        __builtin_amdgcn_sched_barrier(0x7F);    // pin DS ops only

        const __bf16* vcur = vb + (jt & 3) * 2048;
        const bf16x8 vf00 = *reinterpret_cast<const bf16x8*>(vcur + ro + ch0 * 8);
        const bf16x8 vf01 = *reinterpret_cast<const bf16x8*>(vcur + ro + ch1 * 8);
        const bf16x8 vf10 = *reinterpret_cast<const bf16x8*>(vcur + 1024 + ro + ch0 * 8);
        const bf16x8 vf11 = *reinterpret_cast<const bf16x8*>(vcur + 1024 + ro + ch1 * 8);

        const bf16x8 kf0 = *reinterpret_cast<const bf16x8*>(Kbase + (size_t)j0 * NDQK);
        const bf16x8 kf1 = *reinterpret_cast<const bf16x8*>(Kbase + (size_t)j0 * NDQK + 16);

        f32x16 s;
        #pragma unroll
        for (int r = 0; r < 16; ++r) s[r] = 0.f;
        s = __builtin_amdgcn_mfma_f32_32x32x16_bf16(kf0, qf0, s, 0, 0, 0);
        s = __builtin_amdgcn_mfma_f32_32x32x16_bf16(kf1, qf1, s, 0, 0, 0);

        float p[16];
        #pragma unroll
        for (int r = 0; r < 16; ++r) p[r] = __builtin_amdgcn_exp2f(s[r]);

        const float s0 = (p[0] + p[1]) + (p[2] + p[3]);
        const float s1 = (p[4] + p[5]) + (p[6] + p[7]);
        const float s2 = (p[8] + p[9]) + (p[10] + p[11]);
        const float s3 = (p[12] + p[13]) + (p[14] + p[15]);
        lp += (s0 + s1) + (s2 + s3);

        bf16x8 pa0, pa1;
        #pragma unroll
        for (int i = 0; i < 8; ++i) { pa0[i] = (__bf16)p[i]; pa1[i] = (__bf16)p[8 + i]; }

        acc0 = __builtin_amdgcn_mfma_f32_32x32x16_bf16(vf00, pa0, acc0, 0, 0, 0);
        acc0 = __builtin_amdgcn_mfma_f32_32x32x16_bf16(vf01, pa1, acc0, 0, 0, 0);
        acc1 = __builtin_amdgcn_mfma_f32_32x32x16_bf16(vf10, pa0, acc1, 0, 0, 0);
        acc1 = __builtin_amdgcn_mfma_f32_32x32x16_bf16(vf11, pa1, acc1, 0, 0, 0);
    }
    #undef STAGE

    // epilogue: l is lane-local per q after one shfl; direct fused store
    const float lt = lp + __shfl_xor(lp, 32);
    const float gl = gamma[0] / lt;

    #pragma unroll
    for (int r = 0; r < 16; ++r) {
        const int crow = (r & 3) + 8 * (r >> 2) + 4 * hi;
        const size_t g0 = ((size_t)(b * NC + c0w + crow)) * NPOS + q0 + q;
        const size_t g1 = g0 + (size_t)32 * NPOS;
        out[g0] = x[g0] + gl * acc0[r];
        out[g1] = x[g1] + gl * acc1[r];
    }
}

extern "C" void kernel_launch(void* const* d_in, const int* in_sizes, int n_in,
                              void* d_out, int out_size, void* d_ws, size_t ws_size,
                              hipStream_t stream) {
    (void)in_sizes; (void)n_in; (void)out_size; (void)ws_size;
    const float* x     = (const float*)d_in[0];
    const float* Wq    = (const float*)d_in[1];
    const float* bq    = (const float*)d_in[2];
    const float* Wk    = (const float*)d_in[3];
    const float* bk    = (const float*)d_in[4];
    const float* Wv    = (const float*)d_in[5];
    const float* bv    = (const float*)d_in[6];
    const float* gamma = (const float*)d_in[7];
    float* out = (float*)d_out;

    char* ws = (char*)d_ws;
    __hip_bfloat16* Qb = (__hip_bfloat16*)(ws);                    // 1 MB
    __hip_bfloat16* Kb = (__hip_bfloat16*)(ws + (1u << 20));       // 1 MB
    __hip_bfloat16* Vb = (__hip_bfloat16*)(ws + (2u << 20));       // 8 MB

    proj_kernel<<<320, 256, 0, stream>>>(x, Wq, bq, Wk, bk, Wv, bv, Qb, Kb, Vb);
    attn_kernel<<<512, 256, 0, stream>>>(Qb, Kb, Vb, x, gamma, out);
}